// Round 7
// baseline (168.873 us; speedup 1.0000x reference)
//
#include <hip/hip_runtime.h>
#include <math.h>

#define BQ 4096
#define DD 256
#define NNEG 32768

typedef __bf16 bf16x8 __attribute__((ext_vector_type(8)));
typedef float f32x4 __attribute__((ext_vector_type(4)));

// ws layout (floats unless noted):
//   diag[4096] | row_acc[4096] | rpart[64*4096] | cpart[64*4096] |
//   owner[32768] (int) | qb[4096*256] (ushort) | pb[4096*256] (ushort)

__device__ __forceinline__ float get_inv_tau(const float* __restrict__ lt) {
  float tau = __expf(lt[0]);
  tau = fminf(fmaxf(tau, 1e-4f), 1.0f);
  return 1.0f / tau;
}

__device__ __forceinline__ unsigned int f2bf(float f) {
  unsigned int u = __float_as_uint(f);
  u += 0x7FFFu + ((u >> 16) & 1u);  // RNE
  return u >> 16;
}

// ---------- prep: blocks 0..1023 cvt q,p->bf16; block 1024: zero row_acc +
// zero out[0] + scan counts -> owner scatter ----------
__global__ __launch_bounds__(256) void prep_kernel(
    const float* __restrict__ q, const float* __restrict__ p,
    const int* __restrict__ counts,
    ushort* __restrict__ qb, ushort* __restrict__ pb,
    int* __restrict__ owner, float* __restrict__ row_acc,
    float* __restrict__ out) {
  __shared__ int wtot[4];
  const int t = threadIdx.x;
  if (blockIdx.x < 1024) {
    const int i = blockIdx.x * 256 + t;  // 8 elems each
    const int half = (BQ * DD) / 8;      // 131072
    const float* src = (i < half) ? q : p;
    ushort* dst = (i < half) ? qb : pb;
    const int idx = (i < half) ? i : (i - half);
    const float4 a = *reinterpret_cast<const float4*>(&src[idx * 8]);
    const float4 b = *reinterpret_cast<const float4*>(&src[idx * 8 + 4]);
    uint4 o;
    o.x = f2bf(a.x) | (f2bf(a.y) << 16);
    o.y = f2bf(a.z) | (f2bf(a.w) << 16);
    o.z = f2bf(b.x) | (f2bf(b.y) << 16);
    o.w = f2bf(b.z) | (f2bf(b.w) << 16);
    *reinterpret_cast<uint4*>(&dst[idx * 8]) = o;
    return;
  }
  // ---- scan + zero block ----
  const int wid = t >> 6, lane = t & 63;
  const float4 z = {0.f, 0.f, 0.f, 0.f};
#pragma unroll
  for (int i = 0; i < 4; ++i) reinterpret_cast<float4*>(row_acc)[t * 4 + i] = z;
  if (t == 0) out[0] = 0.f;

  int cl[16];
  int s = 0;
#pragma unroll
  for (int i = 0; i < 4; ++i) {
    const int4 c = reinterpret_cast<const int4*>(counts)[t * 4 + i];
    cl[4 * i + 0] = c.x; cl[4 * i + 1] = c.y; cl[4 * i + 2] = c.z; cl[4 * i + 3] = c.w;
    s += c.x + c.y + c.z + c.w;
  }
  int x = s;
#pragma unroll
  for (int off = 1; off < 64; off <<= 1) {
    const int v = __shfl_up(x, off);
    if (lane >= off) x += v;
  }
  if (lane == 63) wtot[wid] = x;
  __syncthreads();
  int base = 0;
  for (int w = 0; w < wid; ++w) base += wtot[w];
  int running = base + x - s;
#pragma unroll
  for (int k = 0; k < 16; ++k) {
    const int qi = 16 * t + k;
    for (int e = 0; e < cl[k]; ++e) owner[running + e] = qi;
    running += cl[k];
  }
}

// ---------- main: blocks [0,512) = negatives (64/block, 4 lanes each);
// blocks [512, 512+4096) = sim 64x64 tiles, 4 waves (32x32 quadrant each),
// direct global frag loads, NO barriers in K-loop, LDS-combined partials ----------
__global__ __launch_bounds__(256) void main_kernel(
    const ushort* __restrict__ qb, const ushort* __restrict__ pb,
    const float* __restrict__ q, const float* __restrict__ n_emb,
    const int* __restrict__ owner, const float* __restrict__ logtau,
    float* __restrict__ diag, float* __restrict__ row_acc,
    float* __restrict__ rpart, float* __restrict__ cpart) {
  __shared__ float rs[64], cs[64];
  const int tid = threadIdx.x;
  const int bid = (int)blockIdx.x;
  const float inv_tau = get_inv_tau(logtau);

  if (bid < 512) {
    // ---------------- negatives ----------------
    const int j = bid * 64 + (tid >> 2);  // negative id
    const int sl = tid & 3;
    const int ow = owner[j];
    const float4* nrow = reinterpret_cast<const float4*>(n_emb + (size_t)j * DD);
    const float4* qrow = reinterpret_cast<const float4*>(q + (size_t)ow * DD);
    float d0 = 0.f, d1 = 0.f;
#pragma unroll
    for (int t2 = 0; t2 < 16; t2 += 2) {
      const float4 n0 = nrow[sl + 4 * t2];
      const float4 q0 = qrow[sl + 4 * t2];
      const float4 n1 = nrow[sl + 4 * (t2 + 1)];
      const float4 q1 = qrow[sl + 4 * (t2 + 1)];
      d0 += q0.x * n0.x + q0.y * n0.y + q0.z * n0.z + q0.w * n0.w;
      d1 += q1.x * n1.x + q1.y * n1.y + q1.z * n1.z + q1.w * n1.w;
    }
    float d = d0 + d1;
    d += __shfl_xor(d, 1);
    d += __shfl_xor(d, 2);
    if (sl == 0) atomicAdd(&row_acc[ow], __expf(d * inv_tau));
    return;
  }

  // ---------------- sim 64x64 tile ----------------
  const int sb = bid - 512;
  const int swz = (sb & 7) * 512 + (sb >> 3);  // bijective XCD swizzle (4096 = 8*512)
  const int bx = swz & 63, by = swz >> 6;
  const int brow = by * 64, bcol = bx * 64;

  const int lane = tid & 63;
  const int wv = tid >> 6;        // 0..3
  const int wr = wv >> 1, wc = wv & 1;
  const int lrow = lane >> 4;     // 0..3
  const int lcol = lane & 15;     // 0..15

  if (tid < 64) { rs[tid] = 0.f; cs[tid] = 0.f; }

  const ushort* ab = qb + (size_t)(brow + wr * 32 + lcol) * DD + lrow * 8;
  const ushort* bb = pb + (size_t)(bcol + wc * 32 + lcol) * DD + lrow * 8;

  f32x4 acc[2][2];
#pragma unroll
  for (int m = 0; m < 2; ++m)
#pragma unroll
    for (int n = 0; n < 2; ++n) acc[m][n] = (f32x4){0.f, 0.f, 0.f, 0.f};

#pragma unroll
  for (int k0 = 0; k0 < DD; k0 += 64) {
    bf16x8 a[2][2], b[2][2];  // [k-substep][frag]
#pragma unroll
    for (int s = 0; s < 2; ++s)
#pragma unroll
      for (int m = 0; m < 2; ++m) {
        a[s][m] = *reinterpret_cast<const bf16x8*>(ab + (size_t)m * 16 * DD + k0 + s * 32);
        b[s][m] = *reinterpret_cast<const bf16x8*>(bb + (size_t)m * 16 * DD + k0 + s * 32);
      }
#pragma unroll
    for (int s = 0; s < 2; ++s)
#pragma unroll
      for (int m = 0; m < 2; ++m)
#pragma unroll
        for (int n = 0; n < 2; ++n)
          acc[m][n] = __builtin_amdgcn_mfma_f32_16x16x32_bf16(a[s][m], b[s][n], acc[m][n], 0, 0, 0);
  }

  __syncthreads();  // rs/cs init visible

  // epilogue: exp + LDS-combined row/col partials + diag
  float colp[2] = {0.f, 0.f};
#pragma unroll
  for (int m = 0; m < 2; ++m) {
    float rowp[4] = {0.f, 0.f, 0.f, 0.f};
#pragma unroll
    for (int n = 0; n < 2; ++n) {
      const f32x4 v = acc[m][n];
#pragma unroll
      for (int r = 0; r < 4; ++r) {
        const float sv = v[r] * inv_tau;
        const float e = __expf(sv);
        const int gr = brow + wr * 32 + m * 16 + lrow * 4 + r;
        const int gc = bcol + wc * 32 + n * 16 + lcol;
        if (gr == gc) diag[gr] = sv;
        rowp[r] += e;
        colp[n] += e;
      }
    }
#pragma unroll
    for (int r = 0; r < 4; ++r) {
      float x = rowp[r];
      x += __shfl_xor(x, 1);
      x += __shfl_xor(x, 2);
      x += __shfl_xor(x, 4);
      x += __shfl_xor(x, 8);
      if (lcol == 0) atomicAdd(&rs[wr * 32 + m * 16 + lrow * 4 + r], x);
    }
  }
#pragma unroll
  for (int n = 0; n < 2; ++n) {
    float x = colp[n];
    x += __shfl_xor(x, 16);
    x += __shfl_xor(x, 32);
    if (lrow == 0) atomicAdd(&cs[wc * 32 + n * 16 + lcol], x);
  }
  __syncthreads();
  if (tid < 64) {
    rpart[(size_t)bx * BQ + brow + tid] = rs[tid];   // unique slot per (bx, row)
    cpart[(size_t)by * BQ + bcol + tid] = cs[tid];   // unique slot per (by, col)
  }
}

// ---------- finalize: 64 blocks, each handles 64 rows; atomicAdd into out ----------
__global__ __launch_bounds__(256) void fin_kernel(
    const float* __restrict__ diag, const float* __restrict__ row_acc,
    const float* __restrict__ rpart, const float* __restrict__ cpart,
    float* __restrict__ out) {
  __shared__ float R[4][64], C[4][64];
  const int k = (int)blockIdx.x, tid = threadIdx.x;
  const int r = tid & 63, w = tid >> 6;
  const int i = k * 64 + r;
  float rt = 0.f, ct = 0.f;
#pragma unroll 4
  for (int t = w; t < 64; t += 4) {
    rt += rpart[(size_t)t * BQ + i];
    ct += cpart[(size_t)t * BQ + i];
  }
  R[w][r] = rt;
  C[w][r] = ct;
  __syncthreads();
  if (tid < 64) {
    const float row_tot = R[0][tid] + R[1][tid] + R[2][tid] + R[3][tid] + row_acc[k * 64 + tid];
    const float col_tot = C[0][tid] + C[1][tid] + C[2][tid] + C[3][tid];
    float v = __logf(row_tot) + __logf(col_tot) - 2.f * diag[k * 64 + tid];
    v += __shfl_xor(v, 1);
    v += __shfl_xor(v, 2);
    v += __shfl_xor(v, 4);
    v += __shfl_xor(v, 8);
    v += __shfl_xor(v, 16);
    v += __shfl_xor(v, 32);
    if (tid == 0) atomicAdd(out, v * (1.f / (2.f * BQ)));
  }
}

extern "C" void kernel_launch(void* const* d_in, const int* in_sizes, int n_in,
                              void* d_out, int out_size, void* d_ws, size_t ws_size,
                              hipStream_t stream) {
  const float* q      = (const float*)d_in[0];
  const float* p      = (const float*)d_in[1];
  const float* n_emb  = (const float*)d_in[2];
  const int*   counts = (const int*)d_in[3];
  const float* logtau = (const float*)d_in[4];
  float* out = (float*)d_out;

  float* ws      = (float*)d_ws;
  float* diag    = ws;                     // [4096]
  float* row_acc = ws + BQ;                // [4096]
  float* rpart   = ws + 2 * BQ;            // [64*4096]
  float* cpart   = rpart + 64 * BQ;        // [64*4096]
  int*   owner   = (int*)(cpart + 64 * BQ);        // [32768]
  ushort* qb     = (ushort*)(owner + NNEG);        // [4096*256]
  ushort* pb     = qb + (size_t)BQ * DD;           // [4096*256]

  prep_kernel<<<1025, 256, 0, stream>>>(q, p, counts, qb, pb, owner, row_acc, out);
  main_kernel<<<512 + 4096, 256, 0, stream>>>(qb, pb, q, n_emb, owner, logtau,
                                              diag, row_acc, rpart, cpart);
  fin_kernel<<<64, 256, 0, stream>>>(diag, row_acc, rpart, cpart, out);
}

// Round 8
// 111.445 us; speedup vs baseline: 1.5153x; 1.5153x over previous
//
#include <hip/hip_runtime.h>
#include <math.h>

#define BQ 4096
#define DD 256
#define NNEG 32768

typedef __bf16 bf16x8 __attribute__((ext_vector_type(8)));
typedef float f32x4 __attribute__((ext_vector_type(4)));

typedef const __attribute__((address_space(1))) void GvPtr;
typedef __attribute__((address_space(3))) void LdsPtr;

// ws layout (floats unless noted):
//   diag[4096] | npart[32768] | rpart[16*4096] | cpart[16*4096] |
//   qb[4096*256] (ushort) | pb[4096*256] (ushort)
// Every slot written every call (poison-proof, no zero-init dispatch).

__device__ __forceinline__ float get_inv_tau(const float* __restrict__ lt) {
  float tau = __expf(lt[0]);
  tau = fminf(fmaxf(tau, 1e-4f), 1.0f);
  return 1.0f / tau;
}

__device__ __forceinline__ unsigned int f2bf(float f) {
  unsigned int u = __float_as_uint(f);
  u += 0x7FFFu + ((u >> 16) & 1u);  // RNE
  return u >> 16;
}

// ---------- prep: blocks [0,1024) cvt q,p -> bf16.
// blocks [1024,1536): 64 negatives each, self-scan of counts (no deps),
// npart[j] = exp(q_ow . n_j / tau). Block 1024 also zeroes out[0]. ----------
__global__ __launch_bounds__(256) void prep_kernel(
    const float* __restrict__ q, const float* __restrict__ p,
    const int* __restrict__ counts, const float* __restrict__ n_emb,
    const float* __restrict__ logtau,
    ushort* __restrict__ qb, ushort* __restrict__ pb,
    float* __restrict__ npart, float* __restrict__ out) {
  __shared__ int P[4096];   // inclusive prefix of counts (neg blocks only)
  __shared__ int wtot[4];
  const int t = threadIdx.x;
  const int bid = (int)blockIdx.x;

  if (bid < 1024) {
    const int i = bid * 256 + t;         // 8 f32 elems each
    const int half = (BQ * DD) / 8;      // 131072
    const float* src = (i < half) ? q : p;
    ushort* dst = (i < half) ? qb : pb;
    const int idx = (i < half) ? i : (i - half);
    const float4 a = *reinterpret_cast<const float4*>(&src[idx * 8]);
    const float4 b = *reinterpret_cast<const float4*>(&src[idx * 8 + 4]);
    uint4 o;
    o.x = f2bf(a.x) | (f2bf(a.y) << 16);
    o.y = f2bf(a.z) | (f2bf(a.w) << 16);
    o.z = f2bf(b.x) | (f2bf(b.y) << 16);
    o.w = f2bf(b.z) | (f2bf(b.w) << 16);
    *reinterpret_cast<uint4*>(&dst[idx * 8]) = o;
    return;
  }

  // ---- negatives ----
  if (bid == 1024 && t == 0) out[0] = 0.f;
  const int lane = t & 63, wid = t >> 6;
  int cl[16];
  int s;
  {
    int run = 0;
#pragma unroll
    for (int i = 0; i < 4; ++i) {
      const int4 cc = reinterpret_cast<const int4*>(counts)[t * 4 + i];
      run += cc.x; cl[4 * i + 0] = run;
      run += cc.y; cl[4 * i + 1] = run;
      run += cc.z; cl[4 * i + 2] = run;
      run += cc.w; cl[4 * i + 3] = run;
    }
    s = run;
  }
  int x = s;
#pragma unroll
  for (int off = 1; off < 64; off <<= 1) {
    const int v = __shfl_up(x, off);
    if (lane >= off) x += v;
  }
  if (lane == 63) wtot[wid] = x;
  __syncthreads();
  int base = 0;
  for (int w = 0; w < wid; ++w) base += wtot[w];
  base += x - s;  // exclusive prefix of query 16*t
#pragma unroll
  for (int k = 0; k < 16; ++k) P[16 * t + k] = base + cl[k];
  __syncthreads();

  const float inv_tau = get_inv_tau(logtau);
  const int j = (bid - 1024) * 64 + (t >> 2);  // negative id
  const int sl = t & 3;
  // owner = first i with P[i] > j
  int lo = 0, hi = 4095;
  while (lo < hi) {
    const int mid = (lo + hi) >> 1;
    if (P[mid] > j) hi = mid; else lo = mid + 1;
  }
  const int ow = lo;
  const float4* nrow = reinterpret_cast<const float4*>(n_emb + (size_t)j * DD);
  const float4* qrow = reinterpret_cast<const float4*>(q + (size_t)ow * DD);
  float d0 = 0.f, d1 = 0.f;
#pragma unroll
  for (int t2 = 0; t2 < 16; t2 += 2) {
    const float4 n0 = nrow[sl + 4 * t2];
    const float4 q0 = qrow[sl + 4 * t2];
    const float4 n1 = nrow[sl + 4 * (t2 + 1)];
    const float4 q1 = qrow[sl + 4 * (t2 + 1)];
    d0 += q0.x * n0.x + q0.y * n0.y + q0.z * n0.z + q0.w * n0.w;
    d1 += q1.x * n1.x + q1.y * n1.y + q1.z * n1.z + q1.w * n1.w;
  }
  float d = d0 + d1;
  d += __shfl_xor(d, 1);
  d += __shfl_xor(d, 2);
  if (sl == 0) npart[j] = __expf(d * inv_tau);
}

// ---------- main: 256 blocks (1/CU), 512 threads (8 waves, 2x4), 256x256 tile,
// BK=64 double-buffered LDS (128 KB), global_load_lds, fused epilogue ----------
__global__ __launch_bounds__(512, 2) void main_kernel(
    const ushort* __restrict__ qb, const ushort* __restrict__ pb,
    const float* __restrict__ logtau,
    float* __restrict__ diag, float* __restrict__ rpart,
    float* __restrict__ cpart) {
  __shared__ ushort As[2][16384];  // [256 rows][64 cols] bf16, 32 KB per buf
  __shared__ ushort Bs[2][16384];

  const int tid = threadIdx.x;
  const int bid = (int)blockIdx.x;
  // XCD swizzle: 256 blocks = 8 XCDs x 32 contiguous
  const int swz = (bid & 7) * 32 + (bid >> 3);
  const int bx = swz & 15, by = swz >> 4;
  const int brow = by * 256, bcol = bx * 256;

  const int lane = tid & 63, wid = tid >> 6;
  const int wr = wid >> 2, wc = wid & 3;      // wave -> 128x64 output
  const int lrow = lane >> 4, lcol = lane & 15;
  const float inv_tau = get_inv_tau(logtau);

  // staging: instruction u covers LDS bytes [u*8192 + tid*16, +16)
  //   -> row u*64 + (tid>>3), col-bytes (tid&7)*16 (8 bf16)
  const int srow = tid >> 3;       // 0..63
  const int scol = (tid & 7) * 8;  // ushort offset

#define STAGE(buf, k0)                                                           \
  {                                                                              \
    _Pragma("unroll")                                                            \
    for (int u = 0; u < 4; ++u) {                                                \
      const ushort* ga = qb + (size_t)(brow + u * 64 + srow) * DD + (k0) + scol; \
      __builtin_amdgcn_global_load_lds((GvPtr*)ga,                               \
          (LdsPtr*)((char*)&As[buf][0] + u * 8192 + tid * 16), 16, 0, 0);        \
      const ushort* gb = pb + (size_t)(bcol + u * 64 + srow) * DD + (k0) + scol; \
      __builtin_amdgcn_global_load_lds((GvPtr*)gb,                               \
          (LdsPtr*)((char*)&Bs[buf][0] + u * 8192 + tid * 16), 16, 0, 0);        \
    }                                                                            \
  }

  f32x4 acc[8][4];
#pragma unroll
  for (int m = 0; m < 8; ++m)
#pragma unroll
    for (int n = 0; n < 4; ++n) acc[m][n] = (f32x4){0.f, 0.f, 0.f, 0.f};

  STAGE(0, 0);
#pragma unroll
  for (int t = 0; t < 4; ++t) {
    __syncthreads();                       // buf[t&1] staged (vmcnt drain here)
    if (t < 3) STAGE((t + 1) & 1, (t + 1) * 64);
    const char* lA = (const char*)&As[t & 1][0];
    const char* lB = (const char*)&Bs[t & 1][0];
#pragma unroll
    for (int sub = 0; sub < 2; ++sub) {
      const int kb = sub * 64 + lrow * 16;  // byte offset in row
      bf16x8 a[8], b[4];
#pragma unroll
      for (int m = 0; m < 8; ++m)
        a[m] = *(const bf16x8*)(lA + (wr * 128 + m * 16 + lcol) * 128 + kb);
#pragma unroll
      for (int n = 0; n < 4; ++n)
        b[n] = *(const bf16x8*)(lB + (wc * 64 + n * 16 + lcol) * 128 + kb);
#pragma unroll
      for (int m = 0; m < 8; ++m)
#pragma unroll
        for (int n = 0; n < 4; ++n)
          acc[m][n] = __builtin_amdgcn_mfma_f32_16x16x32_bf16(a[m], b[n], acc[m][n], 0, 0, 0);
    }
  }
#undef STAGE

  // epilogue: rs/cs overlay on As[0] (t=3 read As[1]/Bs[1]; As[0] is free)
  float* rs = (float*)&As[0][0];       // [256]
  float* cs = rs + 256;                // [256]
  if (tid < 256) rs[tid] = 0.f;
  else cs[tid - 256] = 0.f;
  __syncthreads();

  const int arow0 = brow + wr * 128;
  const int bcol0 = bcol + wc * 64;
  float colp[4] = {0.f, 0.f, 0.f, 0.f};
#pragma unroll
  for (int m = 0; m < 8; ++m) {
    float rowp[4] = {0.f, 0.f, 0.f, 0.f};
#pragma unroll
    for (int n = 0; n < 4; ++n) {
      const f32x4 v = acc[m][n];
#pragma unroll
      for (int r = 0; r < 4; ++r) {
        const float sv = v[r] * inv_tau;
        const float e = __expf(sv);
        const int gr = arow0 + m * 16 + lrow * 4 + r;
        const int gc = bcol0 + n * 16 + lcol;
        if (gr == gc) diag[gr] = sv;
        rowp[r] += e;
        colp[n] += e;
      }
    }
#pragma unroll
    for (int r = 0; r < 4; ++r) {
      float x = rowp[r];
      x += __shfl_xor(x, 1);
      x += __shfl_xor(x, 2);
      x += __shfl_xor(x, 4);
      x += __shfl_xor(x, 8);
      if (lcol == 0) atomicAdd(&rs[wr * 128 + m * 16 + lrow * 4 + r], x);
    }
  }
#pragma unroll
  for (int n = 0; n < 4; ++n) {
    float x = colp[n];
    x += __shfl_xor(x, 16);
    x += __shfl_xor(x, 32);
    if (lrow == 0) atomicAdd(&cs[wc * 64 + n * 16 + lcol], x);
  }
  __syncthreads();
  if (tid < 256) {
    rpart[(size_t)bx * BQ + brow + tid] = rs[tid];   // unique (bx,row)
    cpart[(size_t)by * BQ + bcol + tid] = cs[tid];   // unique (by,col)
  }
}

// ---------- fin: 64 blocks x 64 rows; self-scan counts; atomicAdd into out ----------
__global__ __launch_bounds__(256) void fin_kernel(
    const int* __restrict__ counts, const float* __restrict__ diag,
    const float* __restrict__ npart, const float* __restrict__ rpart,
    const float* __restrict__ cpart, float* __restrict__ out) {
  __shared__ int P[4096];
  __shared__ int wtot[4];
  __shared__ float R[4][64], C[4][64];
  const int t = threadIdx.x, k = (int)blockIdx.x;
  const int lane = t & 63, wid = t >> 6;

  int cl[16];
  int s;
  {
    int run = 0;
#pragma unroll
    for (int i = 0; i < 4; ++i) {
      const int4 cc = reinterpret_cast<const int4*>(counts)[t * 4 + i];
      run += cc.x; cl[4 * i + 0] = run;
      run += cc.y; cl[4 * i + 1] = run;
      run += cc.z; cl[4 * i + 2] = run;
      run += cc.w; cl[4 * i + 3] = run;
    }
    s = run;
  }
  int x = s;
#pragma unroll
  for (int off = 1; off < 64; off <<= 1) {
    const int v = __shfl_up(x, off);
    if (lane >= off) x += v;
  }
  if (lane == 63) wtot[wid] = x;
  __syncthreads();
  int base = 0;
  for (int w = 0; w < wid; ++w) base += wtot[w];
  base += x - s;
#pragma unroll
  for (int kk = 0; kk < 16; ++kk) P[16 * t + kk] = base + cl[kk];

  const int r = t & 63, w = t >> 6;
  const int i = k * 64 + r;
  float rt = 0.f, ct = 0.f;
#pragma unroll
  for (int u = w; u < 16; u += 4) {
    rt += rpart[(size_t)u * BQ + i];
    ct += cpart[(size_t)u * BQ + i];
  }
  R[w][r] = rt;
  C[w][r] = ct;
  __syncthreads();
  if (t < 64) {
    const int i2 = k * 64 + t;
    float row_tot = R[0][t] + R[1][t] + R[2][t] + R[3][t];
    const float col_tot = C[0][t] + C[1][t] + C[2][t] + C[3][t];
    const int off = (i2 == 0) ? 0 : P[i2 - 1];
    const int cnt = P[i2] - off;
    for (int e = 0; e < cnt; ++e) row_tot += npart[off + e];
    float v = __logf(row_tot) + __logf(col_tot) - 2.f * diag[i2];
    v += __shfl_xor(v, 1);
    v += __shfl_xor(v, 2);
    v += __shfl_xor(v, 4);
    v += __shfl_xor(v, 8);
    v += __shfl_xor(v, 16);
    v += __shfl_xor(v, 32);
    if (t == 0) atomicAdd(out, v * (1.f / (2.f * BQ)));
  }
}

extern "C" void kernel_launch(void* const* d_in, const int* in_sizes, int n_in,
                              void* d_out, int out_size, void* d_ws, size_t ws_size,
                              hipStream_t stream) {
  const float* q      = (const float*)d_in[0];
  const float* p      = (const float*)d_in[1];
  const float* n_emb  = (const float*)d_in[2];
  const int*   counts = (const int*)d_in[3];
  const float* logtau = (const float*)d_in[4];
  float* out = (float*)d_out;

  float* ws    = (float*)d_ws;
  float* diag  = ws;                       // [4096]
  float* npart = ws + BQ;                  // [32768]
  float* rpart = npart + NNEG;             // [16*4096]
  float* cpart = rpart + 16 * BQ;          // [16*4096]
  ushort* qb   = (ushort*)(cpart + 16 * BQ);  // [4096*256]
  ushort* pb   = qb + (size_t)BQ * DD;        // [4096*256]

  prep_kernel<<<1536, 256, 0, stream>>>(q, p, counts, n_emb, logtau, qb, pb, npart, out);
  main_kernel<<<256, 512, 0, stream>>>(qb, pb, logtau, diag, rpart, cpart);
  fin_kernel<<<64, 256, 0, stream>>>(counts, diag, npart, rpart, cpart, out);
}